// Round 5
// baseline (594.214 us; speedup 1.0000x reference)
//
#include <hip/hip_runtime.h>
#include <hip/hip_bf16.h>

#define N_NODES  100000
#define N_EDGES  1600000
#define D_FEAT   128
#define HIDDEN   128
#define N_CLASSES 10
#define NUM_GRAPHS 64

#define NBUCK 250        // dst buckets
#define NPB   400        // nodes per bucket (250*400 = 100000)
#define BCAP  7168       // per-bucket edge capacity (mean 6400 + 9.6 sigma)
#define GT    16         // nodes per GEMM block (100000 % 16 == 0)
#define GBLK  (N_NODES / GT)   // 6250 -> same grid as gather (XCD affinity)
#define NPAD  100096     // padded for xconv convenience (kept from prior rounds)

typedef __bf16 bf16x8 __attribute__((ext_vector_type(8)));
typedef float  f32x4  __attribute__((ext_vector_type(4)));

static __device__ __forceinline__ unsigned short f2bf(float f) {
    __bf16 b = (__bf16)f;
    return __builtin_bit_cast(unsigned short, b);
}

// ---------------------------------------------------------------------------
// Convert all 6 fp32 weight matrices to bf16 in one launch.
// ---------------------------------------------------------------------------
__global__ void conv_w6_kernel(const float* __restrict__ W0, const float* __restrict__ W1,
                               const float* __restrict__ W2, const float* __restrict__ W3,
                               const float* __restrict__ W4, const float* __restrict__ W5,
                               __bf16* __restrict__ out) {
    const float* Ws[6] = {W0, W1, W2, W3, W4, W5};
    int m = blockIdx.x >> 6;
    int i = (blockIdx.x & 63) * 256 + threadIdx.x;
    out[m * (HIDDEN * D_FEAT) + i] = (__bf16)Ws[m][i];
}

// ---------------------------------------------------------------------------
// x (fp32) -> bf16, 8 elems/thread; zero-fills the NPAD padding rows.
// ---------------------------------------------------------------------------
__global__ __launch_bounds__(256) void xconv_kernel(const float* __restrict__ x,
                                                    __bf16* __restrict__ out) {
    int i = blockIdx.x * 256 + threadIdx.x;
    bf16x8 o;
    if (i < N_NODES * 128 / 8) {
        float4 v0 = ((const float4*)x)[i * 2];
        float4 v1 = ((const float4*)x)[i * 2 + 1];
        o[0] = (__bf16)v0.x; o[1] = (__bf16)v0.y; o[2] = (__bf16)v0.z; o[3] = (__bf16)v0.w;
        o[4] = (__bf16)v1.x; o[5] = (__bf16)v1.y; o[6] = (__bf16)v1.z; o[7] = (__bf16)v1.w;
    } else {
        #pragma unroll
        for (int k = 0; k < 8; k++) o[k] = (__bf16)0.f;
    }
    if (i < NPAD * 128 / 8) ((bf16x8*)out)[i] = o;
}

// ---------------------------------------------------------------------------
// Pass S: partition edges into bucket-major regions of size BCAP.
// Payload packed into one int: (dst_local << 17) | src   (proven in round 1)
// ---------------------------------------------------------------------------
__global__ __launch_bounds__(256) void bucket_scatter_kernel(const int* __restrict__ ei,
                                                             int* __restrict__ gcur,
                                                             int* __restrict__ bkt) {
    __shared__ int h[NBUCK];
    __shared__ int lb[NBUCK];
    int t = threadIdx.x;
    const int CH = N_EDGES / 256;   // 6250
    for (int i = t; i < NBUCK; i += 256) h[i] = 0;
    __syncthreads();
    int e0 = blockIdx.x * CH;
    for (int e = e0 + t; e < e0 + CH; e += 256) {
        int d = ei[N_EDGES + e];
        atomicAdd(&h[d / NPB], 1);
    }
    __syncthreads();
    for (int i = t; i < NBUCK; i += 256) {
        lb[i] = atomicAdd(&gcur[i], h[i]);
        h[i] = 0;
    }
    __syncthreads();
    for (int e = e0 + t; e < e0 + CH; e += 256) {
        int s = ei[e];
        int d = ei[N_EDGES + e];
        int bb = d / NPB;
        int pos = lb[bb] + atomicAdd(&h[bb], 1);
        if (pos < BCAP) bkt[(size_t)bb * BCAP + pos] = ((d - bb * NPB) << 17) | s;
    }
}

// ---------------------------------------------------------------------------
// Pass D: one block per bucket -> rpse{start,end} + csr_src.
// ---------------------------------------------------------------------------
__global__ __launch_bounds__(256) void bucket_csr_kernel(const int* __restrict__ bkt,
                                                         const int* __restrict__ gcur,
                                                         int2* __restrict__ rpse,
                                                         int* __restrict__ csr_src) {
    const int b = blockIdx.x;
    const int n0 = b * NPB;
    const int base = b * BCAP;
    int m = gcur[b]; if (m > BCAP) m = BCAP;
    __shared__ int cnt[NPB];
    __shared__ int part[128];
    __shared__ int excl[NPB];
    int t = threadIdx.x;
    for (int i = t; i < NPB; i += 256) cnt[i] = 0;
    __syncthreads();
    for (int e = t; e < m; e += 256) {
        int p = bkt[base + e];
        atomicAdd(&cnt[p >> 17], 1);
    }
    __syncthreads();
    int gs = 0;
    if (t < 100) { gs = cnt[4 * t] + cnt[4 * t + 1] + cnt[4 * t + 2] + cnt[4 * t + 3]; part[t] = gs; }
    else if (t < 128) part[t] = 0;
    __syncthreads();
    for (int off = 1; off < 128; off <<= 1) {
        int x = 0;
        if (t < 128 && t >= off) x = part[t - off];
        __syncthreads();
        if (t < 128) part[t] += x;
        __syncthreads();
    }
    if (t < 100) part[t] -= gs;
    __syncthreads();
    for (int i = t; i < NPB; i += 256) {
        int g = i >> 2;
        int e0 = part[g];
        for (int j = g * 4; j < i; j++) e0 += cnt[j];
        excl[i] = e0;
    }
    __syncthreads();
    for (int i = t; i < NPB; i += 256) {
        rpse[n0 + i] = make_int2(base + excl[i], base + excl[i] + cnt[i]);
    }
    __syncthreads();
    for (int i = t; i < NPB; i += 256) cnt[i] = excl[i];   // reuse as cursor
    __syncthreads();
    for (int e = t; e < m; e += 256) {
        int p = bkt[base + e];
        int pos = base + atomicAdd(&cnt[p >> 17], 1);
        csr_src[pos] = p & 0x1FFFF;
    }
}

// ---------------------------------------------------------------------------
// Pure gather-aggregate (verbatim from the 433us baseline; measured 3.6 TB/s):
// agg[n] = sum_j h[csr_src[j]]. 16 lanes/node, 4 nodes/wave, no barriers.
// ---------------------------------------------------------------------------
__global__ __launch_bounds__(256) void gather_kernel(
    const __bf16* __restrict__ h, const int2* __restrict__ rpse,
    const int* __restrict__ csr_src, __bf16* __restrict__ agg, int N)
{
    int nid = blockIdx.x * 16 + (threadIdx.x >> 4);
    if (nid >= N) return;
    int f8 = threadIdx.x & 15;
    int2 se = rpse[nid];

    float a[8] = {0.f, 0.f, 0.f, 0.f, 0.f, 0.f, 0.f, 0.f};

    int j = se.x;
    for (; j + 3 < se.y; j += 4) {
        int s0 = csr_src[j];
        int s1 = csr_src[j + 1];
        int s2 = csr_src[j + 2];
        int s3 = csr_src[j + 3];
        bf16x8 u0 = ((const bf16x8*)h)[(size_t)s0 * 16 + f8];
        bf16x8 u1 = ((const bf16x8*)h)[(size_t)s1 * 16 + f8];
        bf16x8 u2 = ((const bf16x8*)h)[(size_t)s2 * 16 + f8];
        bf16x8 u3 = ((const bf16x8*)h)[(size_t)s3 * 16 + f8];
        #pragma unroll
        for (int i = 0; i < 8; i++)
            a[i] += ((float)u0[i] + (float)u1[i]) + ((float)u2[i] + (float)u3[i]);
    }
    for (; j < se.y; j++) {
        int s0 = csr_src[j];
        bf16x8 u0 = ((const bf16x8*)h)[(size_t)s0 * 16 + f8];
        #pragma unroll
        for (int i = 0; i < 8; i++) a[i] += (float)u0[i];
    }
    bf16x8 o;
    #pragma unroll
    for (int i = 0; i < 8; i++) o[i] = (__bf16)a[i];
    ((bf16x8*)agg)[(size_t)nid * 16 + f8] = o;
}

// ---------------------------------------------------------------------------
// Gather-shaped dual-input GEMM: out = (relu?)(agg@Wl.T + h@Wr.T + b).
// Structure copies what makes the gather fast (rounds 1-4 empirical law:
// per-wave BW is set by continuous, barrier-free per-lane loads; one-shot
// staging + barrier = 3x less BW/wave):
//   - 16-node blocks, grid 6250 (= gather grid -> 3 fill rounds of the 8192
//     wave slots, and producer/consumer XCD affinity for the dirty agg tile)
//   - 4 independent waves, NO LDS, NO __syncthreads
//   - all operands per-lane global loads (fragment math byte-identical to
//     round-2's correctness-proven kernel, tau-loop collapsed)
//   - 4 waves share the block's 8KB feature tile via L1.
// D-layout: col=node (lane&15), row=feat (kq*4+reg).
// POOL variant (layer 3): pooled[batch[node]] += row; h3 never hits HBM.
// ---------------------------------------------------------------------------
template<bool RELU, bool POOL>
__global__ __launch_bounds__(256, 4) void gemm_kernel(
    const __bf16* __restrict__ hA,      // self features [N,128]
    const __bf16* __restrict__ hG,      // aggregated features [N,128]
    const __bf16* __restrict__ Wl, const __bf16* __restrict__ Wr,
    const float* __restrict__ bias,
    __bf16* __restrict__ outp, int M,
    const int* __restrict__ batch, float* __restrict__ pooled)
{
    const int tid  = threadIdx.x;
    const int wave = tid >> 6;
    const int lane = tid & 63;
    const int kq = lane >> 4;
    const int ln = lane & 15;
    const int node_base = blockIdx.x * GT;
    const int f_base = wave * 32;

    const int node = node_base + ln;
    const size_t rowoff = (size_t)node * 128;

    // B-fragments: per-lane direct global loads (proven in round 2)
    bf16x8 gfrag[4], afrag[4];
    #pragma unroll
    for (int kc = 0; kc < 4; kc++) {
        gfrag[kc] = *(const bf16x8*)(hG + rowoff + kc * 32 + kq * 8);
        afrag[kc] = *(const bf16x8*)(hA + rowoff + kc * 32 + kq * 8);
    }

    // W fragments: per-lane loads from L2-hot W (each used exactly once)
    bf16x8 wfragL[2][4], wfragR[2][4];
    #pragma unroll
    for (int t = 0; t < 2; t++) {
        int wrow = f_base + t * 16 + ln;
        #pragma unroll
        for (int kc = 0; kc < 4; kc++) {
            int k0 = kc * 32 + kq * 8;
            wfragL[t][kc] = *(const bf16x8*)(Wl + wrow * 128 + k0);
            wfragR[t][kc] = *(const bf16x8*)(Wr + wrow * 128 + k0);
        }
    }
    float4 bias4[2];
    bias4[0] = *(const float4*)(bias + f_base + kq * 4);
    bias4[1] = *(const float4*)(bias + f_base + 16 + kq * 4);

    f32x4 acc[2] = {(f32x4)(0.f), (f32x4)(0.f)};
    #pragma unroll
    for (int kc = 0; kc < 4; kc++) {
        #pragma unroll
        for (int t = 0; t < 2; t++) {
            acc[t] = __builtin_amdgcn_mfma_f32_16x16x32_bf16(wfragL[t][kc], gfrag[kc], acc[t], 0, 0, 0);
            acc[t] = __builtin_amdgcn_mfma_f32_16x16x32_bf16(wfragR[t][kc], afrag[kc], acc[t], 0, 0, 0);
        }
    }

    if (!POOL) {
        #pragma unroll
        for (int t = 0; t < 2; t++) {
            int fc = f_base + t * 16 + kq * 4;
            float v0 = acc[t][0] + bias4[t].x;
            float v1 = acc[t][1] + bias4[t].y;
            float v2 = acc[t][2] + bias4[t].z;
            float v3 = acc[t][3] + bias4[t].w;
            if (RELU) {
                v0 = fmaxf(v0, 0.f); v1 = fmaxf(v1, 0.f);
                v2 = fmaxf(v2, 0.f); v3 = fmaxf(v3, 0.f);
            }
            ushort4 o;
            o.x = f2bf(v0); o.y = f2bf(v1); o.z = f2bf(v2); o.w = f2bf(v3);
            *(ushort4*)(outp + rowoff + fc) = o;
        }
    } else {
        const int n0 = node_base;
        const bool uni = (batch[n0] == batch[n0 + 15]);   // batch sorted
        #pragma unroll
        for (int t = 0; t < 2; t++) {
            int fc = f_base + t * 16 + kq * 4;
            float v0 = acc[t][0] + bias4[t].x;
            float v1 = acc[t][1] + bias4[t].y;
            float v2 = acc[t][2] + bias4[t].z;
            float v3 = acc[t][3] + bias4[t].w;
            if (uni) {
                // all 16 nodes of this block belong to one graph
                #pragma unroll
                for (int m = 1; m < 16; m <<= 1) {
                    v0 += __shfl_xor(v0, m);
                    v1 += __shfl_xor(v1, m);
                    v2 += __shfl_xor(v2, m);
                    v3 += __shfl_xor(v3, m);
                }
                if (ln == 0) {
                    float* p = &pooled[(size_t)batch[n0] * HIDDEN + fc];
                    unsafeAtomicAdd(p + 0, v0);
                    unsafeAtomicAdd(p + 1, v1);
                    unsafeAtomicAdd(p + 2, v2);
                    unsafeAtomicAdd(p + 3, v3);
                }
            } else {
                float* p = &pooled[(size_t)batch[node] * HIDDEN + fc];
                unsafeAtomicAdd(p + 0, v0);
                unsafeAtomicAdd(p + 1, v1);
                unsafeAtomicAdd(p + 2, v2);
                unsafeAtomicAdd(p + 3, v3);
            }
        }
    }
}

__global__ void final_gemm_kernel(
    const float* __restrict__ pooled, const float* __restrict__ Wout,
    const float* __restrict__ bout, float* __restrict__ out)
{
    int idx = blockIdx.x * 64 + threadIdx.x;
    if (idx < NUM_GRAPHS * N_CLASSES) {
        int g = idx / N_CLASSES;
        int c = idx % N_CLASSES;
        float acc = bout[c];
        for (int k = 0; k < HIDDEN; k++)
            acc += pooled[g * HIDDEN + k] * Wout[c * HIDDEN + k];
        out[idx] = acc;
    }
}

extern "C" void kernel_launch(void* const* d_in, const int* in_sizes, int n_in,
                              void* d_out, int out_size, void* d_ws, size_t ws_size,
                              hipStream_t stream) {
    const float* x     = (const float*)d_in[0];
    const int*   ei    = (const int*)d_in[1];
    const int*   batch = (const int*)d_in[2];
    const float* W1l = (const float*)d_in[3];
    const float* b1  = (const float*)d_in[4];
    const float* W1r = (const float*)d_in[5];
    const float* W2l = (const float*)d_in[6];
    const float* b2  = (const float*)d_in[7];
    const float* W2r = (const float*)d_in[8];
    const float* W3l = (const float*)d_in[9];
    const float* b3  = (const float*)d_in[10];
    const float* W3r = (const float*)d_in[11];
    const float* Wout = (const float*)d_in[12];
    const float* bout = (const float*)d_in[13];
    float* out = (float*)d_out;

    char* ws = (char*)d_ws;
    size_t off = 0;
    const size_t NB = (size_t)NPAD * 128 * sizeof(__bf16);   // 25.6 MB
    __bf16* B0    = (__bf16*)(ws + off); off += NB;   // xbf, later h2
    __bf16* B1    = (__bf16*)(ws + off); off += NB;   // agg (all layers)
    __bf16* B2    = (__bf16*)(ws + off); off += NB;   // h1
    float* pooled = (float*)(ws + off);  off += (size_t)NUM_GRAPHS * HIDDEN * sizeof(float);
    __bf16* wbf   = (__bf16*)(ws + off); off += 6 * (size_t)HIDDEN * D_FEAT * sizeof(__bf16);
    int2* rpse    = (int2*)(ws + off);   off += (size_t)N_NODES * sizeof(int2);
    int* csr_src  = (int*)(ws + off);    off += (size_t)NBUCK * BCAP * sizeof(int);   // 7.2 MB
    int* bkt      = (int*)(ws + off);    off += (size_t)NBUCK * BCAP * sizeof(int);   // 7.2 MB (packed)
    int* gcur     = (int*)(ws + off);    off += (NBUCK + 8) * sizeof(int);

    const int WSZ = HIDDEN * D_FEAT;

    conv_w6_kernel<<<6 * 64, 256, 0, stream>>>(W1l, W1r, W2l, W2r, W3l, W3r, wbf);
    xconv_kernel<<<NPAD * 128 / (256 * 8), 256, 0, stream>>>(x, B0);

    hipMemsetAsync(gcur, 0, NBUCK * sizeof(int), stream);
    hipMemsetAsync(pooled, 0, (size_t)NUM_GRAPHS * HIDDEN * sizeof(float), stream);
    bucket_scatter_kernel<<<256, 256, 0, stream>>>(ei, gcur, bkt);
    bucket_csr_kernel<<<NBUCK, 256, 0, stream>>>(bkt, gcur, rpse, csr_src);

    const int gath_grid = (N_NODES + 15) / 16;   // 6250

    // Layer 1: agg1 = gather(xbf); h1 = relu(agg1@W1l.T + xbf@W1r.T + b1)
    gather_kernel<<<gath_grid, 256, 0, stream>>>(B0, rpse, csr_src, B1, N_NODES);
    gemm_kernel<true, false><<<GBLK, 256, 0, stream>>>(
        B0, B1, wbf + 0 * WSZ, wbf + 1 * WSZ, b1, B2, N_NODES, nullptr, nullptr);

    // Layer 2
    gather_kernel<<<gath_grid, 256, 0, stream>>>(B2, rpse, csr_src, B1, N_NODES);
    gemm_kernel<true, false><<<GBLK, 256, 0, stream>>>(
        B2, B1, wbf + 2 * WSZ, wbf + 3 * WSZ, b2, B0, N_NODES, nullptr, nullptr);

    // Layer 3 (no relu): pooling fused into epilogue; h3 never written
    gather_kernel<<<gath_grid, 256, 0, stream>>>(B0, rpse, csr_src, B1, N_NODES);
    gemm_kernel<false, true><<<GBLK, 256, 0, stream>>>(
        B0, B1, wbf + 4 * WSZ, wbf + 5 * WSZ, b3, nullptr, N_NODES, batch, pooled);

    final_gemm_kernel<<<10, 64, 0, stream>>>(pooled, Wout, bout, out);
}

// Round 6
// 498.620 us; speedup vs baseline: 1.1917x; 1.1917x over previous
//
#include <hip/hip_runtime.h>
#include <hip/hip_bf16.h>

#define N_NODES  100000
#define N_EDGES  1600000
#define D_FEAT   128
#define HIDDEN   128
#define N_CLASSES 10
#define NUM_GRAPHS 64

#define NBUCK 250        // dst buckets
#define NPB   400        // nodes per bucket (250*400 = 100000)
#define BCAP  7168       // per-bucket edge capacity (mean 6400 + 9.6 sigma)
#define GT    64         // nodes per GEMM tile
#define NPAD  100096     // N_NODES padded to GT multiple
#define NTILES (NPAD / GT)   // 1564
#define SORT_CAP 48      // per-node sort depth (P(deg>48) ~ 1e-11; partial sort beyond)

typedef __bf16 bf16x8 __attribute__((ext_vector_type(8)));
typedef float  f32x4  __attribute__((ext_vector_type(4)));

static __device__ __forceinline__ unsigned short f2bf(float f) {
    __bf16 b = (__bf16)f;
    return __builtin_bit_cast(unsigned short, b);
}

// async global->LDS, 16B per lane. LDS dest = wave-uniform base + lane*16.
static __device__ __forceinline__ void async_copy16(void* lds, const void* g) {
    __builtin_amdgcn_global_load_lds(
        (const __attribute__((address_space(1))) void*)g,
        (__attribute__((address_space(3))) void*)lds, 16, 0, 0);
}

// ---------------------------------------------------------------------------
// Convert all 6 fp32 weight matrices to bf16 in one launch.
// ---------------------------------------------------------------------------
__global__ void conv_w6_kernel(const float* __restrict__ W0, const float* __restrict__ W1,
                               const float* __restrict__ W2, const float* __restrict__ W3,
                               const float* __restrict__ W4, const float* __restrict__ W5,
                               __bf16* __restrict__ out) {
    const float* Ws[6] = {W0, W1, W2, W3, W4, W5};
    int m = blockIdx.x >> 6;
    int i = (blockIdx.x & 63) * 256 + threadIdx.x;
    out[m * (HIDDEN * D_FEAT) + i] = (__bf16)Ws[m][i];
}

// ---------------------------------------------------------------------------
// x (fp32) -> bf16, 8 elems/thread; zero-fills the NPAD padding rows.
// ---------------------------------------------------------------------------
__global__ __launch_bounds__(256) void xconv_kernel(const float* __restrict__ x,
                                                    __bf16* __restrict__ out) {
    int i = blockIdx.x * 256 + threadIdx.x;
    bf16x8 o;
    if (i < N_NODES * 128 / 8) {
        float4 v0 = ((const float4*)x)[i * 2];
        float4 v1 = ((const float4*)x)[i * 2 + 1];
        o[0] = (__bf16)v0.x; o[1] = (__bf16)v0.y; o[2] = (__bf16)v0.z; o[3] = (__bf16)v0.w;
        o[4] = (__bf16)v1.x; o[5] = (__bf16)v1.y; o[6] = (__bf16)v1.z; o[7] = (__bf16)v1.w;
    } else {
        #pragma unroll
        for (int k = 0; k < 8; k++) o[k] = (__bf16)0.f;
    }
    if (i < NPAD * 128 / 8) ((bf16x8*)out)[i] = o;
}

// ---------------------------------------------------------------------------
// Pass S: partition edges into bucket-major regions of size BCAP.
// Payload packed into one int: (dst_local << 17) | src   (proven in round 1)
// ---------------------------------------------------------------------------
__global__ __launch_bounds__(256) void bucket_scatter_kernel(const int* __restrict__ ei,
                                                             int* __restrict__ gcur,
                                                             int* __restrict__ bkt) {
    __shared__ int h[NBUCK];
    __shared__ int lb[NBUCK];
    int t = threadIdx.x;
    const int CH = N_EDGES / 256;   // 6250
    for (int i = t; i < NBUCK; i += 256) h[i] = 0;
    __syncthreads();
    int e0 = blockIdx.x * CH;
    for (int e = e0 + t; e < e0 + CH; e += 256) {
        int d = ei[N_EDGES + e];
        atomicAdd(&h[d / NPB], 1);
    }
    __syncthreads();
    for (int i = t; i < NBUCK; i += 256) {
        lb[i] = atomicAdd(&gcur[i], h[i]);
        h[i] = 0;
    }
    __syncthreads();
    for (int e = e0 + t; e < e0 + CH; e += 256) {
        int s = ei[e];
        int d = ei[N_EDGES + e];
        int bb = d / NPB;
        int pos = lb[bb] + atomicAdd(&h[bb], 1);
        if (pos < BCAP) bkt[(size_t)bb * BCAP + pos] = ((d - bb * NPB) << 17) | s;
    }
}

// ---------------------------------------------------------------------------
// Pass D: one block per bucket -> rpse{start,end} + csr_src.
// ---------------------------------------------------------------------------
__global__ __launch_bounds__(256) void bucket_csr_kernel(const int* __restrict__ bkt,
                                                         const int* __restrict__ gcur,
                                                         int2* __restrict__ rpse,
                                                         int* __restrict__ csr_src) {
    const int b = blockIdx.x;
    const int n0 = b * NPB;
    const int base = b * BCAP;
    int m = gcur[b]; if (m > BCAP) m = BCAP;
    __shared__ int cnt[NPB];
    __shared__ int part[128];
    __shared__ int excl[NPB];
    int t = threadIdx.x;
    for (int i = t; i < NPB; i += 256) cnt[i] = 0;
    __syncthreads();
    for (int e = t; e < m; e += 256) {
        int p = bkt[base + e];
        atomicAdd(&cnt[p >> 17], 1);
    }
    __syncthreads();
    int gs = 0;
    if (t < 100) { gs = cnt[4 * t] + cnt[4 * t + 1] + cnt[4 * t + 2] + cnt[4 * t + 3]; part[t] = gs; }
    else if (t < 128) part[t] = 0;
    __syncthreads();
    for (int off = 1; off < 128; off <<= 1) {
        int x = 0;
        if (t < 128 && t >= off) x = part[t - off];
        __syncthreads();
        if (t < 128) part[t] += x;
        __syncthreads();
    }
    if (t < 100) part[t] -= gs;
    __syncthreads();
    for (int i = t; i < NPB; i += 256) {
        int g = i >> 2;
        int e0 = part[g];
        for (int j = g * 4; j < i; j++) e0 += cnt[j];
        excl[i] = e0;
    }
    __syncthreads();
    for (int i = t; i < NPB; i += 256) {
        rpse[n0 + i] = make_int2(base + excl[i], base + excl[i] + cnt[i]);
    }
    __syncthreads();
    for (int i = t; i < NPB; i += 256) cnt[i] = excl[i];   // reuse as cursor
    __syncthreads();
    for (int e = t; e < m; e += 256) {
        int p = bkt[base + e];
        int pos = base + atomicAdd(&cnt[p >> 17], 1);
        csr_src[pos] = p & 0x1FFFF;
    }
}

// ---------------------------------------------------------------------------
// Sort each node's neighbor segment by src id (locality for the gather).
// Order of summands is irrelevant -> correctness-neutral. One thread per
// node; per-thread insertion sort in a private LDS column (bank = tid%32,
// 2 lanes/bank = free). Nodes with deg > SORT_CAP get their first SORT_CAP
// elements sorted among themselves (set preserved).
// ---------------------------------------------------------------------------
__global__ __launch_bounds__(256) void sort_csr_kernel(const int2* __restrict__ rpse,
                                                       int* __restrict__ csr_src, int N) {
    __shared__ int buf[SORT_CAP][256];
    int nid = blockIdx.x * 256 + threadIdx.x;
    if (nid >= N) return;
    int t = threadIdx.x;
    int2 se = rpse[nid];
    int deg = se.y - se.x;
    if (deg <= 1) return;
    if (deg > SORT_CAP) deg = SORT_CAP;
    for (int j = 0; j < deg; j++) buf[j][t] = csr_src[se.x + j];
    for (int i = 1; i < deg; i++) {
        int key = buf[i][t];
        int j = i - 1;
        while (j >= 0 && buf[j][t] > key) { buf[j + 1][t] = buf[j][t]; j--; }
        buf[j + 1][t] = key;
    }
    for (int j = 0; j < deg; j++) csr_src[se.x + j] = buf[j][t];
}

// ---------------------------------------------------------------------------
// Pure gather-aggregate (verbatim from the 433us baseline; 3.6 TB/s there):
// agg[n] = sum_j h[csr_src[j]]. 16 lanes/node, 4 nodes/wave, no barriers.
// With src-sorted lists, step j of all co-resident waves reads a ~6MB
// moving window of h -> L2/L3-resident instead of uniform-random.
// ---------------------------------------------------------------------------
__global__ __launch_bounds__(256) void gather_kernel(
    const __bf16* __restrict__ h, const int2* __restrict__ rpse,
    const int* __restrict__ csr_src, __bf16* __restrict__ agg, int N)
{
    int nid = blockIdx.x * 16 + (threadIdx.x >> 4);
    if (nid >= N) return;
    int f8 = threadIdx.x & 15;
    int2 se = rpse[nid];

    float a[8] = {0.f, 0.f, 0.f, 0.f, 0.f, 0.f, 0.f, 0.f};

    int j = se.x;
    for (; j + 3 < se.y; j += 4) {
        int s0 = csr_src[j];
        int s1 = csr_src[j + 1];
        int s2 = csr_src[j + 2];
        int s3 = csr_src[j + 3];
        bf16x8 u0 = ((const bf16x8*)h)[(size_t)s0 * 16 + f8];
        bf16x8 u1 = ((const bf16x8*)h)[(size_t)s1 * 16 + f8];
        bf16x8 u2 = ((const bf16x8*)h)[(size_t)s2 * 16 + f8];
        bf16x8 u3 = ((const bf16x8*)h)[(size_t)s3 * 16 + f8];
        #pragma unroll
        for (int i = 0; i < 8; i++)
            a[i] += ((float)u0[i] + (float)u1[i]) + ((float)u2[i] + (float)u3[i]);
    }
    for (; j < se.y; j++) {
        int s0 = csr_src[j];
        bf16x8 u0 = ((const bf16x8*)h)[(size_t)s0 * 16 + f8];
        #pragma unroll
        for (int i = 0; i < 8; i++) a[i] += (float)u0[i];
    }
    bf16x8 o;
    #pragma unroll
    for (int i = 0; i < 8; i++) o[i] = (__bf16)a[i];
    ((bf16x8*)agg)[(size_t)nid * 16 + f8] = o;
}

// ---------------------------------------------------------------------------
// Fused dual-input GEMM (exact round-0 433us structure — the best-measured
// gemm across all 6 rounds): out = (relu?)(agg@Wl.T + h@Wr.T + b).
// One block = one 64-node tile, 32KB LDS via global_load_lds (XOR-swizzled),
// W register-resident. D-layout: col=node (lane&15), row=feat (kq*4+reg).
// POOL variant (layer 3, proven in rounds 4-5): pooled[batch[node]] += row;
// h3 never written to HBM. batch sorted -> uniform 16-node groups use a
// 16-lane shfl reduce + one atomic quad; boundary groups per-lane atomics.
// ---------------------------------------------------------------------------
template<bool RELU, bool POOL>
__global__ __launch_bounds__(256) void fused_gemm_kernel(
    const __bf16* __restrict__ hA,      // self features [NPAD,128]
    const __bf16* __restrict__ hG,      // aggregated features [NPAD,128]
    const __bf16* __restrict__ Wl, const __bf16* __restrict__ Wr,
    const float* __restrict__ bias,
    __bf16* __restrict__ outp, int M,
    const int* __restrict__ batch, float* __restrict__ pooled)
{
    __shared__ __bf16 lds[2][GT * 128];   // [0]=agg, [1]=self; 16 KB each

    const int tid  = threadIdx.x;
    const int wave = tid >> 6;
    const int lane = tid & 63;
    const int kq = lane >> 4;
    const int ln = lane & 15;
    const int node_base = blockIdx.x * GT;
    const int f_base = wave * 32;

    // fills: 1024 16B units per tile; unit u: row=u>>4, col16=(u&15)^(row&15)
    {
        const __bf16* gsrc = hG + (size_t)node_base * 128;
        const __bf16* asrc = hA + (size_t)node_base * 128;
        #pragma unroll
        for (int i = 0; i < 4; i++) {
            int u = i * 256 + tid;
            int row = u >> 4;
            int sc = (u & 15) ^ (row & 15);
            async_copy16(&lds[0][u * 8], gsrc + row * 128 + sc * 8);
            async_copy16(&lds[1][u * 8], asrc + row * 128 + sc * 8);
        }
    }

    // W fragments resident (loads overlap the fills; barrier drains both)
    bf16x8 wfragL[2][4], wfragR[2][4];
    #pragma unroll
    for (int t = 0; t < 2; t++) {
        int wrow = f_base + t * 16 + ln;
        #pragma unroll
        for (int kc = 0; kc < 4; kc++) {
            int k0 = kc * 32 + kq * 8;
            wfragL[t][kc] = *(const bf16x8*)(Wl + wrow * 128 + k0);
            wfragR[t][kc] = *(const bf16x8*)(Wr + wrow * 128 + k0);
        }
    }
    float4 bias4[2];
    bias4[0] = *(const float4*)(bias + f_base + kq * 4);
    bias4[1] = *(const float4*)(bias + f_base + 16 + kq * 4);

    __syncthreads();

    #pragma unroll 2
    for (int tau = 0; tau < GT / 16; tau++) {
        int r = tau * 16 + ln;
        bf16x8 gfrag[4], afrag[4];
        #pragma unroll
        for (int kc = 0; kc < 4; kc++) {
            int c = (4 * kc + kq) ^ ln;
            gfrag[kc] = *(const bf16x8*)&lds[0][r * 128 + c * 8];
            afrag[kc] = *(const bf16x8*)&lds[1][r * 128 + c * 8];
        }

        f32x4 acc[2] = {(f32x4)(0.f), (f32x4)(0.f)};
        #pragma unroll
        for (int kc = 0; kc < 4; kc++) {
            #pragma unroll
            for (int t = 0; t < 2; t++) {
                acc[t] = __builtin_amdgcn_mfma_f32_16x16x32_bf16(wfragL[t][kc], gfrag[kc], acc[t], 0, 0, 0);
                acc[t] = __builtin_amdgcn_mfma_f32_16x16x32_bf16(wfragR[t][kc], afrag[kc], acc[t], 0, 0, 0);
            }
        }

        const int node = node_base + tau * 16 + ln;
        if (!POOL) {
            if (node < M) {
                size_t rowoff = (size_t)node * 128;
                #pragma unroll
                for (int t = 0; t < 2; t++) {
                    int fc = f_base + t * 16 + kq * 4;
                    float v0 = acc[t][0] + bias4[t].x;
                    float v1 = acc[t][1] + bias4[t].y;
                    float v2 = acc[t][2] + bias4[t].z;
                    float v3 = acc[t][3] + bias4[t].w;
                    if (RELU) {
                        v0 = fmaxf(v0, 0.f); v1 = fmaxf(v1, 0.f);
                        v2 = fmaxf(v2, 0.f); v3 = fmaxf(v3, 0.f);
                    }
                    ushort4 o;
                    o.x = f2bf(v0); o.y = f2bf(v1); o.z = f2bf(v2); o.w = f2bf(v3);
                    *(ushort4*)(outp + rowoff + fc) = o;
                }
            }
        } else {
            const int n0 = node_base + tau * 16;
            const bool uni = (n0 + 15 < M) && (batch[n0] == batch[n0 + 15]);
            #pragma unroll
            for (int t = 0; t < 2; t++) {
                int fc = f_base + t * 16 + kq * 4;
                float v0 = acc[t][0] + bias4[t].x;
                float v1 = acc[t][1] + bias4[t].y;
                float v2 = acc[t][2] + bias4[t].z;
                float v3 = acc[t][3] + bias4[t].w;
                if (RELU) {
                    v0 = fmaxf(v0, 0.f); v1 = fmaxf(v1, 0.f);
                    v2 = fmaxf(v2, 0.f); v3 = fmaxf(v3, 0.f);
                }
                if (uni) {
                    // all 16 nodes of this group belong to one graph
                    #pragma unroll
                    for (int m = 1; m < 16; m <<= 1) {
                        v0 += __shfl_xor(v0, m);
                        v1 += __shfl_xor(v1, m);
                        v2 += __shfl_xor(v2, m);
                        v3 += __shfl_xor(v3, m);
                    }
                    if (ln == 0) {
                        float* p = &pooled[(size_t)batch[n0] * HIDDEN + fc];
                        unsafeAtomicAdd(p + 0, v0);
                        unsafeAtomicAdd(p + 1, v1);
                        unsafeAtomicAdd(p + 2, v2);
                        unsafeAtomicAdd(p + 3, v3);
                    }
                } else if (node < M) {
                    float* p = &pooled[(size_t)batch[node] * HIDDEN + fc];
                    unsafeAtomicAdd(p + 0, v0);
                    unsafeAtomicAdd(p + 1, v1);
                    unsafeAtomicAdd(p + 2, v2);
                    unsafeAtomicAdd(p + 3, v3);
                }
            }
        }
    }
}

__global__ void final_gemm_kernel(
    const float* __restrict__ pooled, const float* __restrict__ Wout,
    const float* __restrict__ bout, float* __restrict__ out)
{
    int idx = blockIdx.x * 64 + threadIdx.x;
    if (idx < NUM_GRAPHS * N_CLASSES) {
        int g = idx / N_CLASSES;
        int c = idx % N_CLASSES;
        float acc = bout[c];
        for (int k = 0; k < HIDDEN; k++)
            acc += pooled[g * HIDDEN + k] * Wout[c * HIDDEN + k];
        out[idx] = acc;
    }
}

extern "C" void kernel_launch(void* const* d_in, const int* in_sizes, int n_in,
                              void* d_out, int out_size, void* d_ws, size_t ws_size,
                              hipStream_t stream) {
    const float* x     = (const float*)d_in[0];
    const int*   ei    = (const int*)d_in[1];
    const int*   batch = (const int*)d_in[2];
    const float* W1l = (const float*)d_in[3];
    const float* b1  = (const float*)d_in[4];
    const float* W1r = (const float*)d_in[5];
    const float* W2l = (const float*)d_in[6];
    const float* b2  = (const float*)d_in[7];
    const float* W2r = (const float*)d_in[8];
    const float* W3l = (const float*)d_in[9];
    const float* b3  = (const float*)d_in[10];
    const float* W3r = (const float*)d_in[11];
    const float* Wout = (const float*)d_in[12];
    const float* bout = (const float*)d_in[13];
    float* out = (float*)d_out;

    char* ws = (char*)d_ws;
    size_t off = 0;
    const size_t NB = (size_t)NPAD * 128 * sizeof(__bf16);   // 25.6 MB
    __bf16* B0    = (__bf16*)(ws + off); off += NB;   // xbf, later h2
    __bf16* B1    = (__bf16*)(ws + off); off += NB;   // agg (all layers)
    __bf16* B2    = (__bf16*)(ws + off); off += NB;   // h1
    float* pooled = (float*)(ws + off);  off += (size_t)NUM_GRAPHS * HIDDEN * sizeof(float);
    __bf16* wbf   = (__bf16*)(ws + off); off += 6 * (size_t)HIDDEN * D_FEAT * sizeof(__bf16);
    int2* rpse    = (int2*)(ws + off);   off += (size_t)N_NODES * sizeof(int2);
    int* csr_src  = (int*)(ws + off);    off += (size_t)NBUCK * BCAP * sizeof(int);   // 7.2 MB
    int* bkt      = (int*)(ws + off);    off += (size_t)NBUCK * BCAP * sizeof(int);   // 7.2 MB (packed)
    int* gcur     = (int*)(ws + off);    off += (NBUCK + 8) * sizeof(int);

    const int WSZ = HIDDEN * D_FEAT;

    conv_w6_kernel<<<6 * 64, 256, 0, stream>>>(W1l, W1r, W2l, W2r, W3l, W3r, wbf);
    xconv_kernel<<<NPAD * 128 / (256 * 8), 256, 0, stream>>>(x, B0);

    hipMemsetAsync(gcur, 0, NBUCK * sizeof(int), stream);
    hipMemsetAsync(pooled, 0, (size_t)NUM_GRAPHS * HIDDEN * sizeof(float), stream);
    bucket_scatter_kernel<<<256, 256, 0, stream>>>(ei, gcur, bkt);
    bucket_csr_kernel<<<NBUCK, 256, 0, stream>>>(bkt, gcur, rpse, csr_src);
    sort_csr_kernel<<<(N_NODES + 255) / 256, 256, 0, stream>>>(rpse, csr_src, N_NODES);

    const int gath_grid = (N_NODES + 15) / 16;   // 6250

    // Layer 1: agg1 = gather(xbf); h1 = relu(agg1@W1l.T + xbf@W1r.T + b1)
    gather_kernel<<<gath_grid, 256, 0, stream>>>(B0, rpse, csr_src, B1, N_NODES);
    fused_gemm_kernel<true, false><<<NTILES, 256, 0, stream>>>(
        B0, B1, wbf + 0 * WSZ, wbf + 1 * WSZ, b1, B2, N_NODES, nullptr, nullptr);

    // Layer 2
    gather_kernel<<<gath_grid, 256, 0, stream>>>(B2, rpse, csr_src, B1, N_NODES);
    fused_gemm_kernel<true, false><<<NTILES, 256, 0, stream>>>(
        B2, B1, wbf + 2 * WSZ, wbf + 3 * WSZ, b2, B0, N_NODES, nullptr, nullptr);

    // Layer 3 (no relu): pooling fused into epilogue; h3 never written
    gather_kernel<<<gath_grid, 256, 0, stream>>>(B0, rpse, csr_src, B1, N_NODES);
    fused_gemm_kernel<false, true><<<NTILES, 256, 0, stream>>>(
        B0, B1, wbf + 4 * WSZ, wbf + 5 * WSZ, b3, nullptr, N_NODES, batch, pooled);

    final_gemm_kernel<<<10, 64, 0, stream>>>(pooled, Wout, bout, out);
}

// Round 8
// 448.785 us; speedup vs baseline: 1.3241x; 1.1110x over previous
//
#include <hip/hip_runtime.h>
#include <hip/hip_bf16.h>

#define N_NODES  100000
#define N_EDGES  1600000
#define D_FEAT   128
#define HIDDEN   128
#define N_CLASSES 10
#define NUM_GRAPHS 64

#define NBUCK 250        // dst buckets
#define NPB   400        // nodes per bucket (250*400 = 100000)
#define BCAP  7168       // per-bucket edge capacity (mean 6400 + 9.6 sigma)
#define GT    64         // nodes per GEMM tile
#define NPAD  100096     // N_NODES padded to GT multiple
#define NTILES (NPAD / GT)   // 1564

typedef __bf16 bf16x8 __attribute__((ext_vector_type(8)));
typedef float  f32x4  __attribute__((ext_vector_type(4)));

static __device__ __forceinline__ unsigned short f2bf(float f) {
    __bf16 b = (__bf16)f;
    return __builtin_bit_cast(unsigned short, b);
}

// async global->LDS, 16B per lane. LDS dest = wave-uniform base + lane*16.
static __device__ __forceinline__ void async_copy16(void* lds, const void* g) {
    __builtin_amdgcn_global_load_lds(
        (const __attribute__((address_space(1))) void*)g,
        (__attribute__((address_space(3))) void*)lds, 16, 0, 0);
}

// ---------------------------------------------------------------------------
// Convert all 6 fp32 weight matrices to bf16 in one launch.
// ---------------------------------------------------------------------------
__global__ void conv_w6_kernel(const float* __restrict__ W0, const float* __restrict__ W1,
                               const float* __restrict__ W2, const float* __restrict__ W3,
                               const float* __restrict__ W4, const float* __restrict__ W5,
                               __bf16* __restrict__ out) {
    const float* Ws[6] = {W0, W1, W2, W3, W4, W5};
    int m = blockIdx.x >> 6;
    int i = (blockIdx.x & 63) * 256 + threadIdx.x;
    out[m * (HIDDEN * D_FEAT) + i] = (__bf16)Ws[m][i];
}

// ---------------------------------------------------------------------------
// x (fp32) -> bf16, 8 elems/thread; zero-fills the NPAD padding rows.
// ---------------------------------------------------------------------------
__global__ __launch_bounds__(256) void xconv_kernel(const float* __restrict__ x,
                                                    __bf16* __restrict__ out) {
    int i = blockIdx.x * 256 + threadIdx.x;
    bf16x8 o;
    if (i < N_NODES * 128 / 8) {
        float4 v0 = ((const float4*)x)[i * 2];
        float4 v1 = ((const float4*)x)[i * 2 + 1];
        o[0] = (__bf16)v0.x; o[1] = (__bf16)v0.y; o[2] = (__bf16)v0.z; o[3] = (__bf16)v0.w;
        o[4] = (__bf16)v1.x; o[5] = (__bf16)v1.y; o[6] = (__bf16)v1.z; o[7] = (__bf16)v1.w;
    } else {
        #pragma unroll
        for (int k = 0; k < 8; k++) o[k] = (__bf16)0.f;
    }
    if (i < NPAD * 128 / 8) ((bf16x8*)out)[i] = o;
}

// ---------------------------------------------------------------------------
// Pass S: partition edges into bucket-major regions of size BCAP.
// Payload packed into one int: (dst_local << 17) | src   (proven in round 1)
// ---------------------------------------------------------------------------
__global__ __launch_bounds__(256) void bucket_scatter_kernel(const int* __restrict__ ei,
                                                             int* __restrict__ gcur,
                                                             int* __restrict__ bkt) {
    __shared__ int h[NBUCK];
    __shared__ int lb[NBUCK];
    int t = threadIdx.x;
    const int CH = N_EDGES / 256;   // 6250
    for (int i = t; i < NBUCK; i += 256) h[i] = 0;
    __syncthreads();
    int e0 = blockIdx.x * CH;
    for (int e = e0 + t; e < e0 + CH; e += 256) {
        int d = ei[N_EDGES + e];
        atomicAdd(&h[d / NPB], 1);
    }
    __syncthreads();
    for (int i = t; i < NBUCK; i += 256) {
        lb[i] = atomicAdd(&gcur[i], h[i]);
        h[i] = 0;
    }
    __syncthreads();
    for (int e = e0 + t; e < e0 + CH; e += 256) {
        int s = ei[e];
        int d = ei[N_EDGES + e];
        int bb = d / NPB;
        int pos = lb[bb] + atomicAdd(&h[bb], 1);
        if (pos < BCAP) bkt[(size_t)bb * BCAP + pos] = ((d - bb * NPB) << 17) | s;
    }
}

// ---------------------------------------------------------------------------
// Pass D: one block per bucket -> rpse{start,end} + csr_src.
// ---------------------------------------------------------------------------
__global__ __launch_bounds__(256) void bucket_csr_kernel(const int* __restrict__ bkt,
                                                         const int* __restrict__ gcur,
                                                         int2* __restrict__ rpse,
                                                         int* __restrict__ csr_src) {
    const int b = blockIdx.x;
    const int n0 = b * NPB;
    const int base = b * BCAP;
    int m = gcur[b]; if (m > BCAP) m = BCAP;
    __shared__ int cnt[NPB];
    __shared__ int part[128];
    __shared__ int excl[NPB];
    int t = threadIdx.x;
    for (int i = t; i < NPB; i += 256) cnt[i] = 0;
    __syncthreads();
    for (int e = t; e < m; e += 256) {
        int p = bkt[base + e];
        atomicAdd(&cnt[p >> 17], 1);
    }
    __syncthreads();
    int gs = 0;
    if (t < 100) { gs = cnt[4 * t] + cnt[4 * t + 1] + cnt[4 * t + 2] + cnt[4 * t + 3]; part[t] = gs; }
    else if (t < 128) part[t] = 0;
    __syncthreads();
    for (int off = 1; off < 128; off <<= 1) {
        int x = 0;
        if (t < 128 && t >= off) x = part[t - off];
        __syncthreads();
        if (t < 128) part[t] += x;
        __syncthreads();
    }
    if (t < 100) part[t] -= gs;
    __syncthreads();
    for (int i = t; i < NPB; i += 256) {
        int g = i >> 2;
        int e0 = part[g];
        for (int j = g * 4; j < i; j++) e0 += cnt[j];
        excl[i] = e0;
    }
    __syncthreads();
    for (int i = t; i < NPB; i += 256) {
        rpse[n0 + i] = make_int2(base + excl[i], base + excl[i] + cnt[i]);
    }
    __syncthreads();
    for (int i = t; i < NPB; i += 256) cnt[i] = excl[i];   // reuse as cursor
    __syncthreads();
    for (int e = t; e < m; e += 256) {
        int p = bkt[base + e];
        int pos = base + atomicAdd(&cnt[p >> 17], 1);
        csr_src[pos] = p & 0x1FFFF;
    }
}

// ---------------------------------------------------------------------------
// Pure gather-aggregate (the 433us baseline's kernel; measured 3.6 TB/s,
// FETCH ~178MB = ~7x the 25.6MB array = one pass per XCD = the structural
// floor for uniformly-random src reads): agg[n] = sum_j h[csr_src[j]].
// 16 lanes/node, 4 nodes/wave, no barriers.
// ---------------------------------------------------------------------------
__global__ __launch_bounds__(256) void gather_kernel(
    const __bf16* __restrict__ h, const int2* __restrict__ rpse,
    const int* __restrict__ csr_src, __bf16* __restrict__ agg, int N)
{
    int nid = blockIdx.x * 16 + (threadIdx.x >> 4);
    if (nid >= N) return;
    int f8 = threadIdx.x & 15;
    int2 se = rpse[nid];

    float a[8] = {0.f, 0.f, 0.f, 0.f, 0.f, 0.f, 0.f, 0.f};

    int j = se.x;
    for (; j + 3 < se.y; j += 4) {
        int s0 = csr_src[j];
        int s1 = csr_src[j + 1];
        int s2 = csr_src[j + 2];
        int s3 = csr_src[j + 3];
        bf16x8 u0 = ((const bf16x8*)h)[(size_t)s0 * 16 + f8];
        bf16x8 u1 = ((const bf16x8*)h)[(size_t)s1 * 16 + f8];
        bf16x8 u2 = ((const bf16x8*)h)[(size_t)s2 * 16 + f8];
        bf16x8 u3 = ((const bf16x8*)h)[(size_t)s3 * 16 + f8];
        #pragma unroll
        for (int i = 0; i < 8; i++)
            a[i] += ((float)u0[i] + (float)u1[i]) + ((float)u2[i] + (float)u3[i]);
    }
    for (; j < se.y; j++) {
        int s0 = csr_src[j];
        bf16x8 u0 = ((const bf16x8*)h)[(size_t)s0 * 16 + f8];
        #pragma unroll
        for (int i = 0; i < 8; i++) a[i] += (float)u0[i];
    }
    bf16x8 o;
    #pragma unroll
    for (int i = 0; i < 8; i++) o[i] = (__bf16)a[i];
    ((bf16x8*)agg)[(size_t)nid * 16 + f8] = o;
}

// ---------------------------------------------------------------------------
// Fused dual-input GEMM (round-0 structure — best measured across 7 rounds):
// out = (relu?)(agg@Wl.T + h@Wr.T + b). One block = one 64-node tile, 32KB
// LDS via global_load_lds (XOR-swizzled), W register-resident.
// D-layout: col=node (lane&15), row=feat (kq*4+reg).
// POOL variant (layer 3, proven rounds 4-6): pooled[batch[node]] += row;
// h3 never written to HBM. batch sorted -> uniform 16-node groups use a
// 16-lane shfl reduce + one atomic quad; boundary groups per-lane atomics.
// ---------------------------------------------------------------------------
template<bool RELU, bool POOL>
__global__ __launch_bounds__(256) void fused_gemm_kernel(
    const __bf16* __restrict__ hA,      // self features [NPAD,128]
    const __bf16* __restrict__ hG,      // aggregated features [NPAD,128]
    const __bf16* __restrict__ Wl, const __bf16* __restrict__ Wr,
    const float* __restrict__ bias,
    __bf16* __restrict__ outp, int M,
    const int* __restrict__ batch, float* __restrict__ pooled)
{
    __shared__ __bf16 lds[2][GT * 128];   // [0]=agg, [1]=self; 16 KB each

    const int tid  = threadIdx.x;
    const int wave = tid >> 6;
    const int lane = tid & 63;
    const int kq = lane >> 4;
    const int ln = lane & 15;
    const int node_base = blockIdx.x * GT;
    const int f_base = wave * 32;

    // fills: 1024 16B units per tile; unit u: row=u>>4, col16=(u&15)^(row&15)
    {
        const __bf16* gsrc = hG + (size_t)node_base * 128;
        const __bf16* asrc = hA + (size_t)node_base * 128;
        #pragma unroll
        for (int i = 0; i < 4; i++) {
            int u = i * 256 + tid;
            int row = u >> 4;
            int sc = (u & 15) ^ (row & 15);
            async_copy16(&lds[0][u * 8], gsrc + row * 128 + sc * 8);
            async_copy16(&lds[1][u * 8], asrc + row * 128 + sc * 8);
        }
    }

    // W fragments resident (loads overlap the fills; barrier drains both)
    bf16x8 wfragL[2][4], wfragR[2][4];
    #pragma unroll
    for (int t = 0; t < 2; t++) {
        int wrow = f_base + t * 16 + ln;
        #pragma unroll
        for (int kc = 0; kc < 4; kc++) {
            int k0 = kc * 32 + kq * 8;
            wfragL[t][kc] = *(const bf16x8*)(Wl + wrow * 128 + k0);
            wfragR[t][kc] = *(const bf16x8*)(Wr + wrow * 128 + k0);
        }
    }
    float4 bias4[2];
    bias4[0] = *(const float4*)(bias + f_base + kq * 4);
    bias4[1] = *(const float4*)(bias + f_base + 16 + kq * 4);

    __syncthreads();

    #pragma unroll 2
    for (int tau = 0; tau < GT / 16; tau++) {
        int r = tau * 16 + ln;
        bf16x8 gfrag[4], afrag[4];
        #pragma unroll
        for (int kc = 0; kc < 4; kc++) {
            int c = (4 * kc + kq) ^ ln;
            gfrag[kc] = *(const bf16x8*)&lds[0][r * 128 + c * 8];
            afrag[kc] = *(const bf16x8*)&lds[1][r * 128 + c * 8];
        }

        f32x4 acc[2] = {(f32x4)(0.f), (f32x4)(0.f)};
        #pragma unroll
        for (int kc = 0; kc < 4; kc++) {
            #pragma unroll
            for (int t = 0; t < 2; t++) {
                acc[t] = __builtin_amdgcn_mfma_f32_16x16x32_bf16(wfragL[t][kc], gfrag[kc], acc[t], 0, 0, 0);
                acc[t] = __builtin_amdgcn_mfma_f32_16x16x32_bf16(wfragR[t][kc], afrag[kc], acc[t], 0, 0, 0);
            }
        }

        const int node = node_base + tau * 16 + ln;
        if (!POOL) {
            if (node < M) {
                size_t rowoff = (size_t)node * 128;
                #pragma unroll
                for (int t = 0; t < 2; t++) {
                    int fc = f_base + t * 16 + kq * 4;
                    float v0 = acc[t][0] + bias4[t].x;
                    float v1 = acc[t][1] + bias4[t].y;
                    float v2 = acc[t][2] + bias4[t].z;
                    float v3 = acc[t][3] + bias4[t].w;
                    if (RELU) {
                        v0 = fmaxf(v0, 0.f); v1 = fmaxf(v1, 0.f);
                        v2 = fmaxf(v2, 0.f); v3 = fmaxf(v3, 0.f);
                    }
                    ushort4 o;
                    o.x = f2bf(v0); o.y = f2bf(v1); o.z = f2bf(v2); o.w = f2bf(v3);
                    *(ushort4*)(outp + rowoff + fc) = o;
                }
            }
        } else {
            const int n0 = node_base + tau * 16;
            const bool uni = (n0 + 15 < M) && (batch[n0] == batch[n0 + 15]);
            #pragma unroll
            for (int t = 0; t < 2; t++) {
                int fc = f_base + t * 16 + kq * 4;
                float v0 = acc[t][0] + bias4[t].x;
                float v1 = acc[t][1] + bias4[t].y;
                float v2 = acc[t][2] + bias4[t].z;
                float v3 = acc[t][3] + bias4[t].w;
                if (RELU) {
                    v0 = fmaxf(v0, 0.f); v1 = fmaxf(v1, 0.f);
                    v2 = fmaxf(v2, 0.f); v3 = fmaxf(v3, 0.f);
                }
                if (uni) {
                    // all 16 nodes of this group belong to one graph
                    #pragma unroll
                    for (int m = 1; m < 16; m <<= 1) {
                        v0 += __shfl_xor(v0, m);
                        v1 += __shfl_xor(v1, m);
                        v2 += __shfl_xor(v2, m);
                        v3 += __shfl_xor(v3, m);
                    }
                    if (ln == 0) {
                        float* p = &pooled[(size_t)batch[n0] * HIDDEN + fc];
                        unsafeAtomicAdd(p + 0, v0);
                        unsafeAtomicAdd(p + 1, v1);
                        unsafeAtomicAdd(p + 2, v2);
                        unsafeAtomicAdd(p + 3, v3);
                    }
                } else if (node < M) {
                    float* p = &pooled[(size_t)batch[node] * HIDDEN + fc];
                    unsafeAtomicAdd(p + 0, v0);
                    unsafeAtomicAdd(p + 1, v1);
                    unsafeAtomicAdd(p + 2, v2);
                    unsafeAtomicAdd(p + 3, v3);
                }
            }
        }
    }
}

__global__ void final_gemm_kernel(
    const float* __restrict__ pooled, const float* __restrict__ Wout,
    const float* __restrict__ bout, float* __restrict__ out)
{
    int idx = blockIdx.x * 64 + threadIdx.x;
    if (idx < NUM_GRAPHS * N_CLASSES) {
        int g = idx / N_CLASSES;
        int c = idx % N_CLASSES;
        float acc = bout[c];
        for (int k = 0; k < HIDDEN; k++)
            acc += pooled[g * HIDDEN + k] * Wout[c * HIDDEN + k];
        out[idx] = acc;
    }
}

extern "C" void kernel_launch(void* const* d_in, const int* in_sizes, int n_in,
                              void* d_out, int out_size, void* d_ws, size_t ws_size,
                              hipStream_t stream) {
    const float* x     = (const float*)d_in[0];
    const int*   ei    = (const int*)d_in[1];
    const int*   batch = (const int*)d_in[2];
    const float* W1l = (const float*)d_in[3];
    const float* b1  = (const float*)d_in[4];
    const float* W1r = (const float*)d_in[5];
    const float* W2l = (const float*)d_in[6];
    const float* b2  = (const float*)d_in[7];
    const float* W2r = (const float*)d_in[8];
    const float* W3l = (const float*)d_in[9];
    const float* b3  = (const float*)d_in[10];
    const float* W3r = (const float*)d_in[11];
    const float* Wout = (const float*)d_in[12];
    const float* bout = (const float*)d_in[13];
    float* out = (float*)d_out;

    char* ws = (char*)d_ws;
    size_t off = 0;
    const size_t NB = (size_t)NPAD * 128 * sizeof(__bf16);   // 25.6 MB
    __bf16* B0    = (__bf16*)(ws + off); off += NB;   // xbf, later h2
    __bf16* B1    = (__bf16*)(ws + off); off += NB;   // agg (all layers)
    __bf16* B2    = (__bf16*)(ws + off); off += NB;   // h1
    float* pooled = (float*)(ws + off);  off += (size_t)NUM_GRAPHS * HIDDEN * sizeof(float);
    __bf16* wbf   = (__bf16*)(ws + off); off += 6 * (size_t)HIDDEN * D_FEAT * sizeof(__bf16);
    int2* rpse    = (int2*)(ws + off);   off += (size_t)N_NODES * sizeof(int2);
    int* csr_src  = (int*)(ws + off);    off += (size_t)NBUCK * BCAP * sizeof(int);   // 7.2 MB
    int* bkt      = (int*)(ws + off);    off += (size_t)NBUCK * BCAP * sizeof(int);   // 7.2 MB (packed)
    int* gcur     = (int*)(ws + off);    off += (NBUCK + 8) * sizeof(int);

    const int WSZ = HIDDEN * D_FEAT;

    conv_w6_kernel<<<6 * 64, 256, 0, stream>>>(W1l, W1r, W2l, W2r, W3l, W3r, wbf);
    xconv_kernel<<<NPAD * 128 / (256 * 8), 256, 0, stream>>>(x, B0);

    hipMemsetAsync(gcur, 0, NBUCK * sizeof(int), stream);
    hipMemsetAsync(pooled, 0, (size_t)NUM_GRAPHS * HIDDEN * sizeof(float), stream);
    bucket_scatter_kernel<<<256, 256, 0, stream>>>(ei, gcur, bkt);
    bucket_csr_kernel<<<NBUCK, 256, 0, stream>>>(bkt, gcur, rpse, csr_src);

    const int gath_grid = (N_NODES + 15) / 16;   // 6250

    // Layer 1: agg1 = gather(xbf); h1 = relu(agg1@W1l.T + xbf@W1r.T + b1)
    gather_kernel<<<gath_grid, 256, 0, stream>>>(B0, rpse, csr_src, B1, N_NODES);
    fused_gemm_kernel<true, false><<<NTILES, 256, 0, stream>>>(
        B0, B1, wbf + 0 * WSZ, wbf + 1 * WSZ, b1, B2, N_NODES, nullptr, nullptr);

    // Layer 2
    gather_kernel<<<gath_grid, 256, 0, stream>>>(B2, rpse, csr_src, B1, N_NODES);
    fused_gemm_kernel<true, false><<<NTILES, 256, 0, stream>>>(
        B2, B1, wbf + 2 * WSZ, wbf + 3 * WSZ, b2, B0, N_NODES, nullptr, nullptr);

    // Layer 3 (no relu): pooling fused into epilogue; h3 never written
    gather_kernel<<<gath_grid, 256, 0, stream>>>(B0, rpse, csr_src, B1, N_NODES);
    fused_gemm_kernel<false, true><<<NTILES, 256, 0, stream>>>(
        B0, B1, wbf + 4 * WSZ, wbf + 5 * WSZ, b3, nullptr, N_NODES, batch, pooled);

    final_gemm_kernel<<<10, 64, 0, stream>>>(pooled, Wout, bout, out);
}

// Round 9
// 434.608 us; speedup vs baseline: 1.3672x; 1.0326x over previous
//
#include <hip/hip_runtime.h>
#include <hip/hip_bf16.h>

#define N_NODES  100000
#define N_EDGES  1600000
#define D_FEAT   128
#define HIDDEN   128
#define N_CLASSES 10
#define NUM_GRAPHS 64

#define NBUCK 250        // dst buckets
#define NPB   400        // nodes per bucket (250*400 = 100000)
#define BCAP  7168       // per-bucket edge capacity (mean 6400 + 9.6 sigma)
#define GT    64         // nodes per GEMM tile
#define NPAD  100096     // N_NODES padded to GT multiple
#define NTILES (NPAD / GT)   // 1564

typedef __bf16 bf16x8 __attribute__((ext_vector_type(8)));
typedef float  f32x4  __attribute__((ext_vector_type(4)));

static __device__ __forceinline__ unsigned short f2bf(float f) {
    __bf16 b = (__bf16)f;
    return __builtin_bit_cast(unsigned short, b);
}

// async global->LDS, 16B per lane. LDS dest = wave-uniform base + lane*16.
static __device__ __forceinline__ void async_copy16(void* lds, const void* g) {
    __builtin_amdgcn_global_load_lds(
        (const __attribute__((address_space(1))) void*)g,
        (__attribute__((address_space(3))) void*)lds, 16, 0, 0);
}

// ---------------------------------------------------------------------------
// Convert all 6 fp32 weight matrices to bf16 in one launch.
// ---------------------------------------------------------------------------
__global__ void conv_w6_kernel(const float* __restrict__ W0, const float* __restrict__ W1,
                               const float* __restrict__ W2, const float* __restrict__ W3,
                               const float* __restrict__ W4, const float* __restrict__ W5,
                               __bf16* __restrict__ out) {
    const float* Ws[6] = {W0, W1, W2, W3, W4, W5};
    int m = blockIdx.x >> 6;
    int i = (blockIdx.x & 63) * 256 + threadIdx.x;
    out[m * (HIDDEN * D_FEAT) + i] = (__bf16)Ws[m][i];
}

// ---------------------------------------------------------------------------
// x (fp32) -> bf16, 8 elems/thread; zero-fills the NPAD padding rows.
// ---------------------------------------------------------------------------
__global__ __launch_bounds__(256) void xconv_kernel(const float* __restrict__ x,
                                                    __bf16* __restrict__ out) {
    int i = blockIdx.x * 256 + threadIdx.x;
    bf16x8 o;
    if (i < N_NODES * 128 / 8) {
        float4 v0 = ((const float4*)x)[i * 2];
        float4 v1 = ((const float4*)x)[i * 2 + 1];
        o[0] = (__bf16)v0.x; o[1] = (__bf16)v0.y; o[2] = (__bf16)v0.z; o[3] = (__bf16)v0.w;
        o[4] = (__bf16)v1.x; o[5] = (__bf16)v1.y; o[6] = (__bf16)v1.z; o[7] = (__bf16)v1.w;
    } else {
        #pragma unroll
        for (int k = 0; k < 8; k++) o[k] = (__bf16)0.f;
    }
    if (i < NPAD * 128 / 8) ((bf16x8*)out)[i] = o;
}

// ---------------------------------------------------------------------------
// Pass S: partition edges into bucket-major regions of size BCAP.
// Payload packed into one int: (dst_local << 17) | src   (proven in round 1)
// ---------------------------------------------------------------------------
__global__ __launch_bounds__(256) void bucket_scatter_kernel(const int* __restrict__ ei,
                                                             int* __restrict__ gcur,
                                                             int* __restrict__ bkt) {
    __shared__ int h[NBUCK];
    __shared__ int lb[NBUCK];
    int t = threadIdx.x;
    const int CH = N_EDGES / 256;   // 6250
    for (int i = t; i < NBUCK; i += 256) h[i] = 0;
    __syncthreads();
    int e0 = blockIdx.x * CH;
    for (int e = e0 + t; e < e0 + CH; e += 256) {
        int d = ei[N_EDGES + e];
        atomicAdd(&h[d / NPB], 1);
    }
    __syncthreads();
    for (int i = t; i < NBUCK; i += 256) {
        lb[i] = atomicAdd(&gcur[i], h[i]);
        h[i] = 0;
    }
    __syncthreads();
    for (int e = e0 + t; e < e0 + CH; e += 256) {
        int s = ei[e];
        int d = ei[N_EDGES + e];
        int bb = d / NPB;
        int pos = lb[bb] + atomicAdd(&h[bb], 1);
        if (pos < BCAP) bkt[(size_t)bb * BCAP + pos] = ((d - bb * NPB) << 17) | s;
    }
}

// ---------------------------------------------------------------------------
// Pass D: one block per bucket -> rpse{start,end} + csr_src.
// ---------------------------------------------------------------------------
__global__ __launch_bounds__(256) void bucket_csr_kernel(const int* __restrict__ bkt,
                                                         const int* __restrict__ gcur,
                                                         int2* __restrict__ rpse,
                                                         int* __restrict__ csr_src) {
    const int b = blockIdx.x;
    const int n0 = b * NPB;
    const int base = b * BCAP;
    int m = gcur[b]; if (m > BCAP) m = BCAP;
    __shared__ int cnt[NPB];
    __shared__ int part[128];
    __shared__ int excl[NPB];
    int t = threadIdx.x;
    for (int i = t; i < NPB; i += 256) cnt[i] = 0;
    __syncthreads();
    for (int e = t; e < m; e += 256) {
        int p = bkt[base + e];
        atomicAdd(&cnt[p >> 17], 1);
    }
    __syncthreads();
    int gs = 0;
    if (t < 100) { gs = cnt[4 * t] + cnt[4 * t + 1] + cnt[4 * t + 2] + cnt[4 * t + 3]; part[t] = gs; }
    else if (t < 128) part[t] = 0;
    __syncthreads();
    for (int off = 1; off < 128; off <<= 1) {
        int x = 0;
        if (t < 128 && t >= off) x = part[t - off];
        __syncthreads();
        if (t < 128) part[t] += x;
        __syncthreads();
    }
    if (t < 100) part[t] -= gs;
    __syncthreads();
    for (int i = t; i < NPB; i += 256) {
        int g = i >> 2;
        int e0 = part[g];
        for (int j = g * 4; j < i; j++) e0 += cnt[j];
        excl[i] = e0;
    }
    __syncthreads();
    for (int i = t; i < NPB; i += 256) {
        rpse[n0 + i] = make_int2(base + excl[i], base + excl[i] + cnt[i]);
    }
    __syncthreads();
    for (int i = t; i < NPB; i += 256) cnt[i] = excl[i];   // reuse as cursor
    __syncthreads();
    for (int e = t; e < m; e += 256) {
        int p = bkt[base + e];
        int pos = base + atomicAdd(&cnt[p >> 17], 1);
        csr_src[pos] = p & 0x1FFFF;
    }
}

// ---------------------------------------------------------------------------
// Pure gather-aggregate (verbatim R0; measured 3.6 TB/s; FETCH = per-XCD
// touched-rows analytic floor): agg[n] = sum_j h[csr_src[j]].
// ---------------------------------------------------------------------------
__global__ __launch_bounds__(256) void gather_kernel(
    const __bf16* __restrict__ h, const int2* __restrict__ rpse,
    const int* __restrict__ csr_src, __bf16* __restrict__ agg, int N)
{
    int nid = blockIdx.x * 16 + (threadIdx.x >> 4);
    if (nid >= N) return;
    int f8 = threadIdx.x & 15;
    int2 se = rpse[nid];

    float a[8] = {0.f, 0.f, 0.f, 0.f, 0.f, 0.f, 0.f, 0.f};

    int j = se.x;
    for (; j + 3 < se.y; j += 4) {
        int s0 = csr_src[j];
        int s1 = csr_src[j + 1];
        int s2 = csr_src[j + 2];
        int s3 = csr_src[j + 3];
        bf16x8 u0 = ((const bf16x8*)h)[(size_t)s0 * 16 + f8];
        bf16x8 u1 = ((const bf16x8*)h)[(size_t)s1 * 16 + f8];
        bf16x8 u2 = ((const bf16x8*)h)[(size_t)s2 * 16 + f8];
        bf16x8 u3 = ((const bf16x8*)h)[(size_t)s3 * 16 + f8];
        #pragma unroll
        for (int i = 0; i < 8; i++)
            a[i] += ((float)u0[i] + (float)u1[i]) + ((float)u2[i] + (float)u3[i]);
    }
    for (; j < se.y; j++) {
        int s0 = csr_src[j];
        bf16x8 u0 = ((const bf16x8*)h)[(size_t)s0 * 16 + f8];
        #pragma unroll
        for (int i = 0; i < 8; i++) a[i] += (float)u0[i];
    }
    bf16x8 o;
    #pragma unroll
    for (int i = 0; i < 8; i++) o[i] = (__bf16)a[i];
    ((bf16x8*)agg)[(size_t)nid * 16 + f8] = o;
}

// ---------------------------------------------------------------------------
// Fused dual-input GEMM — BYTE-IDENTICAL to the round-0 433.5us kernel
// (template<bool RELU> only; the RELU/POOL sibling template in rounds 6-8
// perturbed codegen per co-compilation rule and cost ~+9us per dispatch).
// out = (relu?)(agg@Wl.T + h@Wr.T + b).
// ---------------------------------------------------------------------------
template<bool RELU>
__global__ __launch_bounds__(256) void fused_gemm_kernel(
    const __bf16* __restrict__ hA,      // self features [NPAD,128]
    const __bf16* __restrict__ hG,      // aggregated features [NPAD,128]
    const __bf16* __restrict__ Wl, const __bf16* __restrict__ Wr,
    const float* __restrict__ bias,
    __bf16* __restrict__ outp, int M)
{
    __shared__ __bf16 lds[2][GT * 128];   // [0]=agg, [1]=self; 16 KB each

    const int tid  = threadIdx.x;
    const int wave = tid >> 6;
    const int lane = tid & 63;
    const int kq = lane >> 4;
    const int ln = lane & 15;
    const int node_base = blockIdx.x * GT;
    const int f_base = wave * 32;

    // fills: 1024 16B units per tile; unit u: row=u>>4, col16=(u&15)^(row&15)
    {
        const __bf16* gsrc = hG + (size_t)node_base * 128;
        const __bf16* asrc = hA + (size_t)node_base * 128;
        #pragma unroll
        for (int i = 0; i < 4; i++) {
            int u = i * 256 + tid;
            int row = u >> 4;
            int sc = (u & 15) ^ (row & 15);
            async_copy16(&lds[0][u * 8], gsrc + row * 128 + sc * 8);
            async_copy16(&lds[1][u * 8], asrc + row * 128 + sc * 8);
        }
    }

    // W fragments resident (loads overlap the fills; barrier drains both)
    bf16x8 wfragL[2][4], wfragR[2][4];
    #pragma unroll
    for (int t = 0; t < 2; t++) {
        int wrow = f_base + t * 16 + ln;
        #pragma unroll
        for (int kc = 0; kc < 4; kc++) {
            int k0 = kc * 32 + kq * 8;
            wfragL[t][kc] = *(const bf16x8*)(Wl + wrow * 128 + k0);
            wfragR[t][kc] = *(const bf16x8*)(Wr + wrow * 128 + k0);
        }
    }
    float4 bias4[2];
    bias4[0] = *(const float4*)(bias + f_base + kq * 4);
    bias4[1] = *(const float4*)(bias + f_base + 16 + kq * 4);

    __syncthreads();

    #pragma unroll 2
    for (int tau = 0; tau < GT / 16; tau++) {
        int r = tau * 16 + ln;
        bf16x8 gfrag[4], afrag[4];
        #pragma unroll
        for (int kc = 0; kc < 4; kc++) {
            int c = (4 * kc + kq) ^ ln;
            gfrag[kc] = *(const bf16x8*)&lds[0][r * 128 + c * 8];
            afrag[kc] = *(const bf16x8*)&lds[1][r * 128 + c * 8];
        }

        f32x4 acc[2] = {(f32x4)(0.f), (f32x4)(0.f)};
        #pragma unroll
        for (int kc = 0; kc < 4; kc++) {
            #pragma unroll
            for (int t = 0; t < 2; t++) {
                acc[t] = __builtin_amdgcn_mfma_f32_16x16x32_bf16(wfragL[t][kc], gfrag[kc], acc[t], 0, 0, 0);
                acc[t] = __builtin_amdgcn_mfma_f32_16x16x32_bf16(wfragR[t][kc], afrag[kc], acc[t], 0, 0, 0);
            }
        }

        int node = node_base + tau * 16 + ln;
        if (node < M) {
            size_t rowoff = (size_t)node * 128;
            #pragma unroll
            for (int t = 0; t < 2; t++) {
                int fc = f_base + t * 16 + kq * 4;
                ushort4 o;
                float v0 = acc[t][0] + bias4[t].x;
                float v1 = acc[t][1] + bias4[t].y;
                float v2 = acc[t][2] + bias4[t].z;
                float v3 = acc[t][3] + bias4[t].w;
                if (RELU) {
                    v0 = fmaxf(v0, 0.f); v1 = fmaxf(v1, 0.f);
                    v2 = fmaxf(v2, 0.f); v3 = fmaxf(v3, 0.f);
                }
                o.x = f2bf(v0); o.y = f2bf(v1); o.z = f2bf(v2); o.w = f2bf(v3);
                *(ushort4*)(outp + rowoff + fc) = o;
            }
        }
    }
}

// ---------------------------------------------------------------------------
// Pool: pooled[batch[n]] += h[n] (bf16 in, fp32 acc/out). batch sorted.
// (verbatim R0)
// ---------------------------------------------------------------------------
__global__ __launch_bounds__(256) void pool_kernel(
    const __bf16* __restrict__ h, const int* __restrict__ batch,
    float* __restrict__ pooled, int N)
{
    int idx = blockIdx.x * 256 + threadIdx.x;
    int f = idx & 127;
    int chunk = idx >> 7;
    int n0 = chunk * 32;
    if (n0 >= N) return;
    int n1 = n0 + 32; if (n1 > N) n1 = N;
    int curb = batch[n0];
    float acc = 0.f;
    for (int n = n0; n < n1; n++) {
        int b = batch[n];
        if (b != curb) {
            unsafeAtomicAdd(&pooled[(size_t)curb * 128 + f], acc);
            acc = 0.f; curb = b;
        }
        acc += (float)h[(size_t)n * 128 + f];
    }
    unsafeAtomicAdd(&pooled[(size_t)curb * 128 + f], acc);
}

__global__ void final_gemm_kernel(
    const float* __restrict__ pooled, const float* __restrict__ Wout,
    const float* __restrict__ bout, float* __restrict__ out)
{
    int idx = blockIdx.x * 64 + threadIdx.x;
    if (idx < NUM_GRAPHS * N_CLASSES) {
        int g = idx / N_CLASSES;
        int c = idx % N_CLASSES;
        float acc = bout[c];
        for (int k = 0; k < HIDDEN; k++)
            acc += pooled[g * HIDDEN + k] * Wout[c * HIDDEN + k];
        out[idx] = acc;
    }
}

extern "C" void kernel_launch(void* const* d_in, const int* in_sizes, int n_in,
                              void* d_out, int out_size, void* d_ws, size_t ws_size,
                              hipStream_t stream) {
    const float* x     = (const float*)d_in[0];
    const int*   ei    = (const int*)d_in[1];
    const int*   batch = (const int*)d_in[2];
    const float* W1l = (const float*)d_in[3];
    const float* b1  = (const float*)d_in[4];
    const float* W1r = (const float*)d_in[5];
    const float* W2l = (const float*)d_in[6];
    const float* b2  = (const float*)d_in[7];
    const float* W2r = (const float*)d_in[8];
    const float* W3l = (const float*)d_in[9];
    const float* b3  = (const float*)d_in[10];
    const float* W3r = (const float*)d_in[11];
    const float* Wout = (const float*)d_in[12];
    const float* bout = (const float*)d_in[13];
    float* out = (float*)d_out;

    char* ws = (char*)d_ws;
    size_t off = 0;
    const size_t NB = (size_t)NPAD * 128 * sizeof(__bf16);   // 25.6 MB
    __bf16* B0    = (__bf16*)(ws + off); off += NB;   // xbf, later h2
    __bf16* B1    = (__bf16*)(ws + off); off += NB;   // agg (all layers)
    __bf16* B2    = (__bf16*)(ws + off); off += NB;   // h1, h3
    float* pooled = (float*)(ws + off);  off += (size_t)NUM_GRAPHS * HIDDEN * sizeof(float);
    __bf16* wbf   = (__bf16*)(ws + off); off += 6 * (size_t)HIDDEN * D_FEAT * sizeof(__bf16);
    int2* rpse    = (int2*)(ws + off);   off += (size_t)N_NODES * sizeof(int2);
    int* csr_src  = (int*)(ws + off);    off += (size_t)NBUCK * BCAP * sizeof(int);   // 7.2 MB
    int* bkt      = (int*)(ws + off);    off += (size_t)NBUCK * BCAP * sizeof(int);   // 7.2 MB (packed)
    int* gcur     = (int*)(ws + off);    off += (NBUCK + 8) * sizeof(int);

    const int WSZ = HIDDEN * D_FEAT;

    conv_w6_kernel<<<6 * 64, 256, 0, stream>>>(W1l, W1r, W2l, W2r, W3l, W3r, wbf);
    xconv_kernel<<<NPAD * 128 / (256 * 8), 256, 0, stream>>>(x, B0);

    hipMemsetAsync(gcur, 0, NBUCK * sizeof(int), stream);
    bucket_scatter_kernel<<<256, 256, 0, stream>>>(ei, gcur, bkt);
    bucket_csr_kernel<<<NBUCK, 256, 0, stream>>>(bkt, gcur, rpse, csr_src);

    const int gath_grid = (N_NODES + 15) / 16;   // 6250

    // Layer 1: agg1 = gather(xbf); h1 = relu(agg1@W1l.T + xbf@W1r.T + b1)
    gather_kernel<<<gath_grid, 256, 0, stream>>>(B0, rpse, csr_src, B1, N_NODES);
    fused_gemm_kernel<true><<<NTILES, 256, 0, stream>>>(
        B0, B1, wbf + 0 * WSZ, wbf + 1 * WSZ, b1, B2, N_NODES);

    // Layer 2
    gather_kernel<<<gath_grid, 256, 0, stream>>>(B2, rpse, csr_src, B1, N_NODES);
    fused_gemm_kernel<true><<<NTILES, 256, 0, stream>>>(
        B2, B1, wbf + 2 * WSZ, wbf + 3 * WSZ, b2, B0, N_NODES);

    // Layer 3 (no relu)
    gather_kernel<<<gath_grid, 256, 0, stream>>>(B0, rpse, csr_src, B1, N_NODES);
    fused_gemm_kernel<false><<<NTILES, 256, 0, stream>>>(
        B0, B1, wbf + 4 * WSZ, wbf + 5 * WSZ, b3, B2, N_NODES);

    // Pool + final
    hipMemsetAsync(pooled, 0, (size_t)NUM_GRAPHS * HIDDEN * sizeof(float), stream);
    const int pool_grid = ((N_NODES + 31) / 32 * 128 + 255) / 256;
    pool_kernel<<<pool_grid, 256, 0, stream>>>(B2, batch, pooled, N_NODES);
    final_gemm_kernel<<<10, 64, 0, stream>>>(pooled, Wout, bout, out);
}